// Round 5
// baseline (1289.327 us; speedup 1.0000x reference)
//
#include <hip/hip_runtime.h>
#include <hip/hip_bf16.h>
#include <stdint.h>

// Problem constants (fixed by setup_inputs)
#define NTOK   8192
#define TOPK   2
#define NEXP   8
#define DIN    2048
#define DOUT   2048
#define NK     (NTOK*TOPK)

// GEMM tiling: 256(M) x 256(N) tile, BK=32, 8 waves as 2(M) x 4(N),
// wave tile 128x64 = 8x4 MFMA 16x16x32 bf16 frags.
// Economy 32.8 FLOP/LDS-byte (vs 23.8 at 256x128) AND 2 blocks/CU (the
// variable that separated R3=39% from R1/R2/R4=31-33%: gather-latency
// stragglers need a co-resident block to hide behind).
#define BM 256
#define BN 256
#define BK 32
#define KTILES   (DIN/BK)          // 64
#define ABYTES   (BM*BK*2)         // 16 KB per K-tile of A
#define BUFBYTES 32768             // A 16 KB | B 16 KB per slot
#define NBUF 2                     // 64 KB ring -> 2 blocks/CU

typedef __bf16 bf16_8 __attribute__((ext_vector_type(8)));  // 4 VGPRs, MFMA A/B frag
typedef float  f32x4  __attribute__((ext_vector_type(4)));  // MFMA C/D frag

#define N8W (NEXP*DOUT*DIN/8)      // 4194304 uint4 outputs for W
#define N8X (NTOK*DIN/8)           // 2097152 uint4 outputs for X

// global->LDS direct load, 16B per lane. LDS dest = wave-uniform base + lane*16.
__device__ __forceinline__ void gl2lds16(const void* g, void* l) {
  auto gp = reinterpret_cast<const __attribute__((address_space(1))) uint32_t*>(
      reinterpret_cast<uintptr_t>(g));
  auto lp = reinterpret_cast<__attribute__((address_space(3))) uint32_t*>(
      reinterpret_cast<uintptr_t>(l));
  __builtin_amdgcn_global_load_lds(gp, lp, 16, 0, 0);
}

// Fused fp32 -> bf16 (RNE) for W then X. Grid-stride at 2048 blocks (G11:
// memory-bound ops want ~2048 blocks + grid-stride, not 24576 one-shot blocks).
__global__ __launch_bounds__(256)
void cvt_all(const float4* __restrict__ w, uint4* __restrict__ wD,
             const float4* __restrict__ x, uint4* __restrict__ xD) {
  const int stride = gridDim.x * blockDim.x;
  for (int i = blockIdx.x * blockDim.x + threadIdx.x; i < N8W + N8X; i += stride) {
    const float4* src;
    uint4* dst;
    int j;
    if (i < N8W) { src = w; dst = wD; j = i; }
    else         { src = x; dst = xD; j = i - N8W; }
    float4 a0 = src[2 * j];
    float4 a1 = src[2 * j + 1];
    union { __bf16 h[8]; uint4 u; } r;
    r.h[0] = (__bf16)a0.x; r.h[1] = (__bf16)a0.y; r.h[2] = (__bf16)a0.z; r.h[3] = (__bf16)a0.w;
    r.h[4] = (__bf16)a1.x; r.h[5] = (__bf16)a1.y; r.h[6] = (__bf16)a1.z; r.h[7] = (__bf16)a1.w;
    dst[j] = r.u;
  }
}

// Grouped GEMM over expert-sorted flat rows.
// 256x256 tile, NBUF=2 double buffer, single 32-MFMA phase per K-tile:
//   stage(t+1) -> buf[cur^1]  (4 gload_lds; WAR-safe: buf[cur^1]'s tile t-1
//                              reads all completed before end-of-(t-1) barrier)
//   ds_read af[0..7], bf[0..3] of buf[cur]  (compiler-counted lgkmcnt)
//   32 x MFMA
//   s_waitcnt vmcnt(0); s_barrier   (t+1 resident; drain covered by the
//                                    sibling block on this CU + ~1-tile issue
//                                    distance; 1-blk/CU variants lacked this)
// Tables/staging/frag/epilogue addressing verbatim from R2/R4 (refcheck-passed).
//
// LDS bank-conflict swizzle (measured 0 conflicts): row r's 16B chunk q lives
// at chunk slot q ^ s(r), s(r) = (r>>1)&3. Staging lane loads global chunk
// (tid&3)^((tid>>3)&3); reader xors kq by (lr>>1)&3. s(r) invariant under
// r += multiples of 8 -> one formula serves all waves/frags/halves.
__global__ __launch_bounds__(512, 4)
void moe_gemm(const __bf16* __restrict__ X,     // [NTOK, DIN] bf16
              const __bf16* __restrict__ W,     // [NEXP, DOUT, DIN] bf16 (B^T form)
              const int* __restrict__ ssi,      // sorted_scattered_idxs [NK]
              const int* __restrict__ offs,     // expert_offsets [NEXP]
              __bf16* __restrict__ flat)        // [NK, DOUT] bf16 out (ungated)
{
  __shared__ char lds[NBUF * BUFBYTES];   // 64 KB ring: per slot A 16K | B 16K
  __shared__ int  sTok[BM];
  __shared__ int  sF[BM];

  const int tid = threadIdx.x;
  const int bid = blockIdx.x;
  const int nt  = bid & 7;          // 8 N-tiles of 256
  const int mtg = bid >> 3;         // linear M-tile over all experts

  // Map linear M-tile -> (expert e, tile-in-segment). Uniform scan of 8 offsets.
  int start = 0, end = 0, e, cum = 0, prev = 0, mloc = 0, found = 0;
  for (e = 0; e < NEXP; ++e) {
    int oe  = offs[e];
    int seg = oe - prev;
    int t   = (seg + BM - 1) >> 8;
    if (mtg < cum + t) { start = prev; end = oe; mloc = mtg - cum; found = 1; break; }
    cum += t; prev = oe;
  }
  if (!found) return;  // pad block (uniform exit)

  const int m0 = start + mloc * BM;

  if (tid < BM) {
    int p     = m0 + tid;
    int valid = p < end;
    int f     = ssi[valid ? p : (end - 1)];  // clamp keeps gather in-bounds
    sTok[tid] = f >> 1;                      // token = flat / k (k=2)
    sF[tid]   = valid ? f : -1;
  }
  __syncthreads();   // tables visible before staging reads them

  // Staging (verbatim from R2, refcheck-passed): thread tid owns rows rs and
  // rs+128 of both A and B, swizzled k-chunk kc. LDS dest linear: slice+lane*16.
  const int rs = tid >> 2;                       // 0..127
  const int kc = (tid & 3) ^ ((tid >> 3) & 3);   // swizzled chunk
  const __bf16* pA0 = X + (size_t)sTok[rs]       * DIN + kc * 8;
  const __bf16* pA1 = X + (size_t)sTok[rs + 128] * DIN + kc * 8;
  const __bf16* wBp = W + (size_t)e * DOUT * DIN + (size_t)(nt * BN) * DIN;
  const __bf16* pB0 = wBp + (size_t)rs * DIN + kc * 8;
  const __bf16* pB1 = wBp + (size_t)(rs + 128) * DIN + kc * 8;
  char* wsl = (char*)lds + (tid >> 6) * 1024;    // wave-uniform slice base

  // Prologue: stage tile 0 into slot 0.
  gl2lds16(pA0, wsl);           gl2lds16(pA1, wsl + 8192);
  gl2lds16(pB0, wsl + 16384);   gl2lds16(pB1, wsl + 24576);
  pA0 += BK; pA1 += BK; pB0 += BK; pB1 += BK;

  // Fragment addressing (verbatim from R2). A frag: lane holds A[m][k=kq*8+j].
  const int w   = tid >> 6;
  const int l   = tid & 63;
  const int wm  = w >> 2, wn = w & 3;            // 2 x 4 wave grid
  const int lr  = l & 15;
  const int kq  = l >> 4;
  const int kqs = kq ^ ((lr >> 1) & 3);          // bank-conflict swizzle
  const char* aBase = (const char*)lds + (wm * 128 + lr) * 64 + kqs * 16;
  const char* bBase = (const char*)lds + ABYTES + (wn * 64 + lr) * 64 + kqs * 16;

  asm volatile("s_waitcnt vmcnt(0)" ::: "memory");
  __builtin_amdgcn_s_barrier();

  f32x4 acc[8][4] = {};
  int cur = 0;

  for (int t = 0; t < KTILES; ++t) {
    // Issue next-tile stage first (VMEM issue cheap; ~1 tile of cover).
    if (t < KTILES - 1) {
      char* d = wsl + (cur ^ 1) * BUFBYTES;
      gl2lds16(pA0, d);           gl2lds16(pA1, d + 8192);
      gl2lds16(pB0, d + 16384);   gl2lds16(pB1, d + 24576);
      pA0 += BK; pA1 += BK; pB0 += BK; pB1 += BK;
    }

    const char* aB = aBase + cur * BUFBYTES;
    const char* bB = bBase + cur * BUFBYTES;
    bf16_8 af[8], bf[4];
#pragma unroll
    for (int i = 0; i < 8; ++i) af[i] = *(const bf16_8*)(aB + i * 1024);  // rows wm*128+i*16
#pragma unroll
    for (int i = 0; i < 4; ++i) bf[i] = *(const bf16_8*)(bB + i * 1024);  // cols wn*64+i*16

#pragma unroll
    for (int am = 0; am < 8; ++am)
#pragma unroll
      for (int bn = 0; bn < 4; ++bn)
        acc[am][bn] = __builtin_amdgcn_mfma_f32_16x16x32_bf16(
            af[am], bf[bn], acc[am][bn], 0, 0, 0);

    if (t < KTILES - 1) {
      asm volatile("s_waitcnt vmcnt(0)" ::: "memory");  // tile t+1 resident
      __builtin_amdgcn_s_barrier();                      // + all reads of cur done
      cur ^= 1;
    }
  }

  // Epilogue (verbatim from R2): C/D layout col=lane&15, row=(lane>>4)*4+reg.
  const int colBase = nt * BN + wn * 64 + lr;
  const int rq = kq * 4;
#pragma unroll
  for (int am = 0; am < 8; ++am) {
#pragma unroll
    for (int v = 0; v < 4; ++v) {
      int rl = wm * 128 + am * 16 + rq + v;
      int f  = sF[rl];
      if (f < 0) continue;
      __bf16* row = flat + (size_t)f * DOUT + colBase;
#pragma unroll
      for (int bn = 0; bn < 4; ++bn)
        row[bn * 16] = (__bf16)acc[am][bn][v];
    }
  }
}

// out[n, :] = g[2n]*flat[2n, :] + g[2n+1]*flat[2n+1, :]
// Grid-stride at 2048 blocks (G11).
__global__ __launch_bounds__(256)
void combine(const __bf16* __restrict__ flat, const float* __restrict__ gates,
             float* __restrict__ out) {
  const int stride = gridDim.x * blockDim.x;
  for (int idx = blockIdx.x * blockDim.x + threadIdx.x; idx < NTOK * (DOUT / 8);
       idx += stride) {
    const int n = idx >> 8;              // token
    const int c = (idx & 255) * 8;       // column chunk
    bf16_8 y0 = *(const bf16_8*)(flat + (size_t)(2 * n)     * DOUT + c);
    bf16_8 y1 = *(const bf16_8*)(flat + (size_t)(2 * n + 1) * DOUT + c);
    const float2 g = *(const float2*)(gates + 2 * n);
    float o[8];
#pragma unroll
    for (int j = 0; j < 8; ++j)
      o[j] = g.x * (float)y0[j] + g.y * (float)y1[j];
    float4* dst = (float4*)(out + (size_t)n * DOUT + c);
    dst[0] = *(float4*)&o[0];
    dst[1] = *(float4*)&o[4];
  }
}

extern "C" void kernel_launch(void* const* d_in, const int* in_sizes, int n_in,
                              void* d_out, int out_size, void* d_ws, size_t ws_size,
                              hipStream_t stream) {
  const float* inputs = (const float*)d_in[0];   // [8192, 2048]
  const float* ew     = (const float*)d_in[1];   // [8, 2048, 2048] (E, out, in)
  const float* gates  = (const float*)d_in[2];   // [8192, 2]
  const int*   ssi    = (const int*)d_in[5];     // sorted_scattered_idxs [16384]
  const int*   offs   = (const int*)d_in[6];     // expert_offsets [8]
  float* out = (float*)d_out;

  // ws layout: bf16 W (64 MB) | bf16 X (32 MB) | bf16 flat out (64 MB)
  __bf16* wsW = (__bf16*)d_ws;
  __bf16* wsX = wsW + (size_t)NEXP * DOUT * DIN;
  __bf16* wsF = wsX + (size_t)NTOK * DIN;

  cvt_all<<<2048, 256, 0, stream>>>((const float4*)ew, (uint4*)wsW,
                                    (const float4*)inputs, (uint4*)wsX);

  // max M-tiles = 64 + 8 (per-expert ceil padding), 8 N-tiles of 256
  moe_gemm<<<72 * 8, 512, 0, stream>>>(wsX, wsW, ssi, offs, wsF);
  combine<<<2048, 256, 0, stream>>>(wsF, gates, out);
}

// Round 6
// 478.057 us; speedup vs baseline: 2.6970x; 2.6970x over previous
//
#include <hip/hip_runtime.h>
#include <hip/hip_bf16.h>
#include <stdint.h>

// Problem constants (fixed by setup_inputs)
#define NTOK   8192
#define TOPK   2
#define NEXP   8
#define DIN    2048
#define DOUT   2048
#define NK     (NTOK*TOPK)

// GEMM tiling: 256(M) x 128(N) tile, BK=32, 8 waves as 4(M) x 2(N),
// wave tile 64x64 = 4x4 MFMA 16x16x32 bf16 frags.
// REGISTER LESSON (R5): unified VGPR+AGPR pool is 512/SIMD. 64-reg acc + ~52
// working regs x 4 waves/SIMD = fits; a 128-reg acc (256-wide tile) cannot
// have 2 blocks/CU and spills at launch_bounds(512,4) (R5: 1.9 GB scratch).
// R3 geometry (166 us, 39.4% MfmaUtil) is the proven optimum of that trade.
#define BM 256
#define BN 128
#define BK 32
#define KTILES  (DIN/BK)           // 64
#define SLOT    24576              // per-K-tile LDS: A 16 KB + B 8 KB
#define NBUF    3                  // 72 KB ring, prefetch depth 2 tiles

typedef __bf16 bf16_8 __attribute__((ext_vector_type(8)));  // 4 VGPRs, MFMA A/B frag
typedef float  f32x4  __attribute__((ext_vector_type(4)));  // MFMA C/D frag

// global->LDS direct load, 16B per lane. LDS dest = wave-uniform base + lane*16.
__device__ __forceinline__ void gl2lds16(const void* g, void* l) {
  auto gp = reinterpret_cast<const __attribute__((address_space(1))) uint32_t*>(
      reinterpret_cast<uintptr_t>(g));
  auto lp = reinterpret_cast<__attribute__((address_space(3))) uint32_t*>(
      reinterpret_cast<uintptr_t>(l));
  __builtin_amdgcn_global_load_lds(gp, lp, 16, 0, 0);
}

// Fused fp32 -> bf16 (RNE) for W then X. 8 elems/thread, 16B stores.
// (R0 form — one-shot grid; grid-stride variant measured identical.)
__global__ void cvt_all(const float4* __restrict__ w, uint4* __restrict__ wD,
                        const float4* __restrict__ x, uint4* __restrict__ xD,
                        int nW) {
  int b = blockIdx.x;
  const float4* src;
  uint4* dst;
  int i;
  if (b < nW) { src = w; dst = wD; i = b * 256 + threadIdx.x; }
  else        { src = x; dst = xD; i = (b - nW) * 256 + threadIdx.x; }
  float4 a0 = src[2 * i];
  float4 a1 = src[2 * i + 1];
  union { __bf16 h[8]; uint4 u; } r;
  r.h[0] = (__bf16)a0.x; r.h[1] = (__bf16)a0.y; r.h[2] = (__bf16)a0.z; r.h[3] = (__bf16)a0.w;
  r.h[4] = (__bf16)a1.x; r.h[5] = (__bf16)a1.y; r.h[6] = (__bf16)a1.z; r.h[7] = (__bf16)a1.w;
  dst[i] = r.u;
}

// Grouped GEMM over expert-sorted flat rows — R3 schedule (verbatim) +
// (a) XCD-aware bijective block swizzle: the 16 blocks sharing one gathered
//     A-panel (same mtg, all nt) land on the same XCD's L2 (T1; grid%8==0).
// (b) fused gated epilogue: out[tok] += gates[f] * acc via f32 atomic add —
//     replaces the bf16 flat buffer + combine kernel (-128 MB HBM round trip,
//     -1 kernel, better precision). out is zeroed by a memset before launch.
//
// Per K-tile t (counted-vmcnt NBUF=3 ring, proven in R3):
//   stage(t+2) -> slot (t+2)%3   (3 gload_lds; WAR-safe per R3 comment)
//   ds_read af[0..3], bf[0..3] of tile t; 16 x MFMA
//   s_waitcnt vmcnt(3)           (tile t+1 landed; t+2's 3 stay in flight)
//   s_barrier
// Tail: vmcnt(0) at t=KTILES-2; no sync after last tile.
//
// LDS bank-conflict swizzle (measured 0 conflicts): row r's 16B chunk q lives
// at chunk slot q ^ s(r), s(r) = (r>>1)&3. Staging lane loads global chunk
// (tid&3)^((tid>>3)&3); reader xors kq by (lr>>1)&3.
__global__ __launch_bounds__(512, 4)
void moe_gemm(const __bf16* __restrict__ X,     // [NTOK, DIN] bf16
              const __bf16* __restrict__ W,     // [NEXP, DOUT, DIN] bf16 (B^T form)
              const int* __restrict__ ssi,      // sorted_scattered_idxs [NK]
              const int* __restrict__ offs,     // expert_offsets [NEXP]
              const float* __restrict__ gates,  // [NTOK, TOPK] fp32 (flat [NK])
              float* __restrict__ out)          // [NTOK, DOUT] fp32, pre-zeroed
{
  __shared__ char lds[NBUF * SLOT];   // 72 KB ring: per slot A 16 KB | B 8 KB
  __shared__ int  sTok[BM];
  __shared__ int  sF[BM];

  const int tid = threadIdx.x;
  // XCD swizzle: HW assigns XCD = blockIdx % 8; remap so one XCD owns a
  // contiguous chunk of work ids -> same-mtg blocks share an L2. 1152%8==0.
  const int nwg = gridDim.x;
  const int b0  = blockIdx.x;
  const int bid = (b0 & 7) * (nwg >> 3) + (b0 >> 3);
  const int nt  = bid & 15;         // 16 N-tiles of 128
  const int mtg = bid >> 4;         // linear M-tile over all experts

  // Map linear M-tile -> (expert e, tile-in-segment). Uniform scan of 8 offsets.
  int start = 0, end = 0, e, cum = 0, prev = 0, mloc = 0, found = 0;
  for (e = 0; e < NEXP; ++e) {
    int oe  = offs[e];
    int seg = oe - prev;
    int t   = (seg + BM - 1) >> 8;
    if (mtg < cum + t) { start = prev; end = oe; mloc = mtg - cum; found = 1; break; }
    cum += t; prev = oe;
  }
  if (!found) return;  // pad block (uniform exit)

  const int m0 = start + mloc * BM;

  if (tid < BM) {
    int p     = m0 + tid;
    int valid = p < end;
    int f     = ssi[valid ? p : (end - 1)];  // clamp keeps gather in-bounds
    sTok[tid] = f >> 1;                      // token = flat / k (k=2)
    sF[tid]   = valid ? f : -1;
  }
  __syncthreads();   // tables visible; full drain -> clean slate for counted regime

  // Staging: thread tid owns A rows rs = tid>>2 and rs+128, B row rs,
  // swizzled k-chunk kc. LDS dest linear: wave slice base + lane*16.
  const int rs = tid >> 2;                       // 0..127
  const int kc = (tid & 3) ^ ((tid >> 3) & 3);   // swizzled chunk
  const __bf16* pA0 = X + (size_t)sTok[rs]       * DIN + kc * 8;
  const __bf16* pA1 = X + (size_t)sTok[rs + 128] * DIN + kc * 8;
  const __bf16* wBp = W + (size_t)e * DOUT * DIN + (size_t)(nt * BN) * DIN;
  const __bf16* pB0 = wBp + (size_t)rs * DIN + kc * 8;
  char* wsl = (char*)lds + (tid >> 6) * 1024;    // wave-uniform slice base

  // Prologue: stage tiles 0,1 into slots 0,1 (6 loads in flight).
  gl2lds16(pA0, wsl);           gl2lds16(pA1, wsl + 8192);
  gl2lds16(pB0, wsl + 16384);
  pA0 += BK; pA1 += BK; pB0 += BK;
  gl2lds16(pA0, wsl + SLOT);    gl2lds16(pA1, wsl + SLOT + 8192);
  gl2lds16(pB0, wsl + SLOT + 16384);
  pA0 += BK; pA1 += BK; pB0 += BK;   // now at tile-2 source offset

  // Fragment addressing. A frag: lane holds A[m=lr][k=kq*8+j]; LDS row = 64 B.
  const int w   = tid >> 6;
  const int l   = tid & 63;
  const int wm  = w >> 1, wn = w & 1;            // 4 x 2 wave grid
  const int lr  = l & 15;
  const int kq  = l >> 4;
  const int kqs = kq ^ ((lr >> 1) & 3);          // bank-conflict swizzle
  const char* aBase = (const char*)lds + (wm * 64 + lr) * 64 + kqs * 16;
  const char* bBase = (const char*)lds + 16384 + (wn * 64 + lr) * 64 + kqs * 16;

  // Tile 0 arrival: own 3 oldest loads done (tile 1's may stay in flight).
  asm volatile("s_waitcnt vmcnt(3)" ::: "memory");
  __builtin_amdgcn_s_barrier();

  f32x4 acc[4][4] = {};
  int rOff = 0;               // read slot byte offset (t % 3)
  int sOff = 2 * SLOT;        // stage slot byte offset ((t+2) % 3)

  for (int t = 0; t < KTILES; ++t) {
    // Issue next prefetch first (maximizes cover; 3 VMEM issues are cheap).
    if (t < KTILES - 2) {
      char* d = wsl + sOff;
      gl2lds16(pA0, d);  gl2lds16(pA1, d + 8192);  gl2lds16(pB0, d + 16384);
      pA0 += BK; pA1 += BK; pB0 += BK;
      sOff = (sOff == (NBUF - 1) * SLOT) ? 0 : sOff + SLOT;
    }

    const char* aB = aBase + rOff;
    const char* bB = bBase + rOff;
    rOff = (rOff == (NBUF - 1) * SLOT) ? 0 : rOff + SLOT;

    bf16_8 af[4], bf[4];
#pragma unroll
    for (int i = 0; i < 4; ++i) af[i] = *(const bf16_8*)(aB + i * 1024);  // rows i*16
#pragma unroll
    for (int i = 0; i < 4; ++i) bf[i] = *(const bf16_8*)(bB + i * 1024);  // cols i*16

#pragma unroll
    for (int am = 0; am < 4; ++am)
#pragma unroll
      for (int bn = 0; bn < 4; ++bn)
        acc[am][bn] = __builtin_amdgcn_mfma_f32_16x16x32_bf16(
            af[am], bf[bn], acc[am][bn], 0, 0, 0);

    // Arrival of tile t+1 for next iteration; never drain until the tail.
    if (t < KTILES - 2)       { asm volatile("s_waitcnt vmcnt(3)" ::: "memory"); }
    else if (t == KTILES - 2) { asm volatile("s_waitcnt vmcnt(0)" ::: "memory"); }
    if (t < KTILES - 1) __builtin_amdgcn_s_barrier();
  }

  // Fused gated epilogue: C/D layout col=lane&15, row=(lane>>4)*4+reg.
  // out[f>>1, col] += gates[f] * acc  (f32 HW atomic; 2 disjoint adds/elem).
  const int colBase = nt * BN + wn * 64 + lr;
  const int rq = kq * 4;
#pragma unroll
  for (int am = 0; am < 4; ++am) {
#pragma unroll
    for (int v = 0; v < 4; ++v) {
      int rl = wm * 64 + am * 16 + rq + v;
      int f  = sF[rl];
      if (f < 0) continue;
      float g = gates[f];
      float* row = out + (size_t)(f >> 1) * DOUT + colBase;
#pragma unroll
      for (int bn = 0; bn < 4; ++bn)
        unsafeAtomicAdd(&row[bn * 16], g * acc[am][bn][v]);
    }
  }
}

extern "C" void kernel_launch(void* const* d_in, const int* in_sizes, int n_in,
                              void* d_out, int out_size, void* d_ws, size_t ws_size,
                              hipStream_t stream) {
  const float* inputs = (const float*)d_in[0];   // [8192, 2048]
  const float* ew     = (const float*)d_in[1];   // [8, 2048, 2048] (E, out, in)
  const float* gates  = (const float*)d_in[2];   // [8192, 2]
  const int*   ssi    = (const int*)d_in[5];     // sorted_scattered_idxs [16384]
  const int*   offs   = (const int*)d_in[6];     // expert_offsets [8]
  float* out = (float*)d_out;

  // ws layout: bf16 W (64 MB) | bf16 X (32 MB)
  __bf16* wsW = (__bf16*)d_ws;
  __bf16* wsX = wsW + (size_t)NEXP * DOUT * DIN;

  // Zero the f32 output (gemm accumulates atomically into it).
  hipMemsetAsync(out, 0, (size_t)NTOK * DOUT * sizeof(float), stream);

  const int n8w = NEXP * DOUT * DIN / 8;   // 4194304 -> 16384 blocks
  const int n8x = NTOK * DIN / 8;          // 2097152 ->  8192 blocks
  const int nWb = n8w / 256, nXb = n8x / 256;
  cvt_all<<<nWb + nXb, 256, 0, stream>>>((const float4*)ew, (uint4*)wsW,
                                         (const float4*)inputs, (uint4*)wsX, nWb);

  // max M-tiles = 64 + 8 (per-expert ceil padding), 16 N-tiles of 128
  moe_gemm<<<72 * 16, 512, 0, stream>>>(wsX, wsW, ssi, offs, gates, out);
}

// Round 7
// 444.552 us; speedup vs baseline: 2.9003x; 1.0754x over previous
//
#include <hip/hip_runtime.h>
#include <hip/hip_bf16.h>
#include <stdint.h>

// Problem constants (fixed by setup_inputs)
#define NTOK   8192
#define TOPK   2
#define NEXP   8
#define DIN    2048
#define DOUT   2048
#define NK     (NTOK*TOPK)

// GEMM tiling: 256(M) x 128(N) tile, BK=32, 8 waves as 4(M) x 2(N),
// wave tile 64x64 = 2x2 MFMA 32x32x16 bf16 frags (was 4x4 of 16x16x32:
// same LDS bytes, same 64 acc + 32 frag regs, but 8 MFMA/K-tile instead of
// 16 -> 64.6 cy vs 77.6 cy pipe time and half the issue/dep pressure;
// m119: 32x32 ceiling 2495 TF vs 16x16's 2176).
// REGISTER LESSON (R5): unified VGPR+AGPR pool is 512/SIMD; 64-reg acc is
// the max that allows 4 waves/SIMD (2 blocks/CU) — 128-reg acc spills.
// OCCUPANCY LESSON (R1/R2/R4): 1-block/CU lockstep caps at ~33% MfmaUtil;
// the gather's latency stragglers need a co-resident block to hide behind.
#define BM 256
#define BN 128
#define BK 32
#define KTILES  (DIN/BK)           // 64
#define SLOT    24576              // per-K-tile LDS: A 16 KB + B 8 KB
#define NBUF    3                  // 72 KB ring, prefetch depth 2 tiles

typedef __bf16 bf16_8 __attribute__((ext_vector_type(8)));   // 4 VGPRs, MFMA A/B frag
typedef float  f32x16 __attribute__((ext_vector_type(16)));  // 32x32 MFMA C/D frag

// global->LDS direct load, 16B per lane. LDS dest = wave-uniform base + lane*16.
__device__ __forceinline__ void gl2lds16(const void* g, void* l) {
  auto gp = reinterpret_cast<const __attribute__((address_space(1))) uint32_t*>(
      reinterpret_cast<uintptr_t>(g));
  auto lp = reinterpret_cast<__attribute__((address_space(3))) uint32_t*>(
      reinterpret_cast<uintptr_t>(l));
  __builtin_amdgcn_global_load_lds(gp, lp, 16, 0, 0);
}

// Fused fp32 -> bf16 (RNE) for W then X. 8 elems/thread, 16B stores.
__global__ void cvt_all(const float4* __restrict__ w, uint4* __restrict__ wD,
                        const float4* __restrict__ x, uint4* __restrict__ xD,
                        int nW) {
  int b = blockIdx.x;
  const float4* src;
  uint4* dst;
  int i;
  if (b < nW) { src = w; dst = wD; i = b * 256 + threadIdx.x; }
  else        { src = x; dst = xD; i = (b - nW) * 256 + threadIdx.x; }
  float4 a0 = src[2 * i];
  float4 a1 = src[2 * i + 1];
  union { __bf16 h[8]; uint4 u; } r;
  r.h[0] = (__bf16)a0.x; r.h[1] = (__bf16)a0.y; r.h[2] = (__bf16)a0.z; r.h[3] = (__bf16)a0.w;
  r.h[4] = (__bf16)a1.x; r.h[5] = (__bf16)a1.y; r.h[6] = (__bf16)a1.z; r.h[7] = (__bf16)a1.w;
  dst[i] = r.u;
}

// Grouped GEMM over expert-sorted flat rows — R3 schedule (verbatim) +
// XCD-aware bijective block swizzle (R6-proven: FETCH 288->189 MB) +
// 32x32x16 MFMA shape. Flat bf16 output + combine kernel (R6's atomic
// epilogue reverted: 64 scalar f32 atomics/thread doubled WRITE and cost
// +55 us).
//
// Per K-tile t (counted-vmcnt NBUF=3 ring, proven in R3):
//   stage(t+2) -> slot (t+2)%3   (3 gload_lds; WAR-safe: slot (t-1)%3's
//                                 reads were consumed before end-of-(t-1)
//                                 barrier, and this issue is after it)
//   ds_read a[2][2], b[2][2] of tile t; 8 x MFMA 32x32x16
//   s_waitcnt vmcnt(3)           (tile t+1 landed; t+2's 3 stay in flight)
//   s_barrier
// Tail: vmcnt(0) at t=KTILES-2; no sync after last tile.
//
// LDS bank-conflict swizzle: row r's 16B chunk q lives at chunk slot
// q ^ s(r), s(r) = (r>>1)&3. Staging lane loads global chunk
// (tid&3)^((tid>>3)&3); reader xors its chunk by s. s(r) invariant under
// r += multiples of 8 -> serves the 32-row frags too (row%8 unchanged).
__global__ __launch_bounds__(512, 4)
void moe_gemm(const __bf16* __restrict__ X,     // [NTOK, DIN] bf16
              const __bf16* __restrict__ W,     // [NEXP, DOUT, DIN] bf16 (B^T form)
              const int* __restrict__ ssi,      // sorted_scattered_idxs [NK]
              const int* __restrict__ offs,     // expert_offsets [NEXP]
              __bf16* __restrict__ flat)        // [NK, DOUT] bf16 out (ungated)
{
  __shared__ char lds[NBUF * SLOT];   // 72 KB ring: per slot A 16 KB | B 8 KB
  __shared__ int  sTok[BM];
  __shared__ int  sF[BM];

  const int tid = threadIdx.x;
  // XCD swizzle: HW assigns XCD = blockIdx % 8; remap so one XCD owns a
  // contiguous chunk of work ids -> same-mtg blocks share an L2. 1152%8==0.
  const int nwg = gridDim.x;
  const int b0  = blockIdx.x;
  const int bid = (b0 & 7) * (nwg >> 3) + (b0 >> 3);
  const int nt  = bid & 15;         // 16 N-tiles of 128
  const int mtg = bid >> 4;         // linear M-tile over all experts

  // Map linear M-tile -> (expert e, tile-in-segment). Uniform scan of 8 offsets.
  int start = 0, end = 0, e, cum = 0, prev = 0, mloc = 0, found = 0;
  for (e = 0; e < NEXP; ++e) {
    int oe  = offs[e];
    int seg = oe - prev;
    int t   = (seg + BM - 1) >> 8;
    if (mtg < cum + t) { start = prev; end = oe; mloc = mtg - cum; found = 1; break; }
    cum += t; prev = oe;
  }
  if (!found) return;  // pad block (uniform exit)

  const int m0 = start + mloc * BM;

  if (tid < BM) {
    int p     = m0 + tid;
    int valid = p < end;
    int f     = ssi[valid ? p : (end - 1)];  // clamp keeps gather in-bounds
    sTok[tid] = f >> 1;                      // token = flat / k (k=2)
    sF[tid]   = valid ? f : -1;
  }
  __syncthreads();   // tables visible; full drain -> clean slate for counted regime

  // Staging: thread tid owns A rows rs = tid>>2 and rs+128, B row rs,
  // swizzled k-chunk kc. LDS dest linear: wave slice base + lane*16.
  const int rs = tid >> 2;                       // 0..127
  const int kc = (tid & 3) ^ ((tid >> 3) & 3);   // swizzled chunk
  const __bf16* pA0 = X + (size_t)sTok[rs]       * DIN + kc * 8;
  const __bf16* pA1 = X + (size_t)sTok[rs + 128] * DIN + kc * 8;
  const __bf16* wBp = W + (size_t)e * DOUT * DIN + (size_t)(nt * BN) * DIN;
  const __bf16* pB0 = wBp + (size_t)rs * DIN + kc * 8;
  char* wsl = (char*)lds + (tid >> 6) * 1024;    // wave-uniform slice base

  // Prologue: stage tiles 0,1 into slots 0,1 (6 loads in flight).
  gl2lds16(pA0, wsl);           gl2lds16(pA1, wsl + 8192);
  gl2lds16(pB0, wsl + 16384);
  pA0 += BK; pA1 += BK; pB0 += BK;
  gl2lds16(pA0, wsl + SLOT);    gl2lds16(pA1, wsl + SLOT + 8192);
  gl2lds16(pB0, wsl + SLOT + 16384);
  pA0 += BK; pA1 += BK; pB0 += BK;   // now at tile-2 source offset

  // Fragment addressing for 32x32x16: lane holds A[row=l&31][k=(l>>5)*8+j];
  // per k-step ks the 16B chunk index is c = 2*ks + (l>>5), swizzled c^s.
  const int w   = tid >> 6;
  const int l   = tid & 63;
  const int wm  = w >> 1, wn = w & 1;            // 4 x 2 wave grid
  const int r32 = l & 31;
  const int h   = l >> 5;
  const int s   = (r32 >> 1) & 3;                // bank-conflict swizzle
  const int co0 = ((2 * 0 + h) ^ s) * 16;        // ks=0 chunk byte offset
  const int co1 = ((2 * 1 + h) ^ s) * 16;        // ks=1 chunk byte offset
  const char* aBase = (const char*)lds + (wm * 64 + r32) * 64;
  const char* bBase = (const char*)lds + 16384 + (wn * 64 + r32) * 64;

  // Tile 0 arrival: own 3 oldest loads done (tile 1's may stay in flight).
  asm volatile("s_waitcnt vmcnt(3)" ::: "memory");
  __builtin_amdgcn_s_barrier();

  f32x16 acc[2][2] = {};
  int rOff = 0;               // read slot byte offset (t % 3)
  int sOff = 2 * SLOT;        // stage slot byte offset ((t+2) % 3)

  for (int t = 0; t < KTILES; ++t) {
    // Issue next prefetch first (maximizes cover; 3 VMEM issues are cheap).
    if (t < KTILES - 2) {
      char* d = wsl + sOff;
      gl2lds16(pA0, d);  gl2lds16(pA1, d + 8192);  gl2lds16(pB0, d + 16384);
      pA0 += BK; pA1 += BK; pB0 += BK;
      sOff = (sOff == (NBUF - 1) * SLOT) ? 0 : sOff + SLOT;
    }

    const char* aB = aBase + rOff;
    const char* bB = bBase + rOff;
    rOff = (rOff == (NBUF - 1) * SLOT) ? 0 : rOff + SLOT;

    bf16_8 a0[2], a1[2], bb0[2], bb1[2];   // [mi]/[ni], ks split
#pragma unroll
    for (int mi = 0; mi < 2; ++mi) {
      a0[mi] = *(const bf16_8*)(aB + mi * 2048 + co0);   // rows +mi*32, ks=0
      a1[mi] = *(const bf16_8*)(aB + mi * 2048 + co1);   // ks=1
    }
#pragma unroll
    for (int ni = 0; ni < 2; ++ni) {
      bb0[ni] = *(const bf16_8*)(bB + ni * 2048 + co0);  // cols +ni*32, ks=0
      bb1[ni] = *(const bf16_8*)(bB + ni * 2048 + co1);  // ks=1
    }

#pragma unroll
    for (int mi = 0; mi < 2; ++mi)
#pragma unroll
      for (int ni = 0; ni < 2; ++ni) {
        acc[mi][ni] = __builtin_amdgcn_mfma_f32_32x32x16_bf16(
            a0[mi], bb0[ni], acc[mi][ni], 0, 0, 0);
        acc[mi][ni] = __builtin_amdgcn_mfma_f32_32x32x16_bf16(
            a1[mi], bb1[ni], acc[mi][ni], 0, 0, 0);
      }

    // Arrival of tile t+1 for next iteration; never drain until the tail.
    if (t < KTILES - 2)       { asm volatile("s_waitcnt vmcnt(3)" ::: "memory"); }
    else if (t == KTILES - 2) { asm volatile("s_waitcnt vmcnt(0)" ::: "memory"); }
    if (t < KTILES - 1) __builtin_amdgcn_s_barrier();
  }

  // Epilogue: 32x32 C/D layout col=lane&31, row=(reg&3)+8*(reg>>2)+4*(lane>>5)
  // (m74/m101-verified). Plain bf16 stores, ungated; gate in combine kernel.
  const int colBase = nt * BN + wn * 64 + r32;
#pragma unroll
  for (int mi = 0; mi < 2; ++mi) {
#pragma unroll
    for (int reg = 0; reg < 16; ++reg) {
      int q  = reg >> 2, v = reg & 3;
      int rl = wm * 64 + mi * 32 + q * 8 + v + h * 4;
      int f  = sF[rl];
      if (f < 0) continue;
      __bf16* row = flat + (size_t)f * DOUT + colBase;
#pragma unroll
      for (int ni = 0; ni < 2; ++ni)
        row[ni * 32] = (__bf16)acc[mi][ni][reg];
    }
  }
}

// out[n, :] = g[2n]*flat[2n, :] + g[2n+1]*flat[2n+1, :]
__global__ __launch_bounds__(256)
void combine(const __bf16* __restrict__ flat, const float* __restrict__ gates,
             float* __restrict__ out) {
  const int n = blockIdx.x;
  const int c = threadIdx.x * 8;
  bf16_8 y0 = *(const bf16_8*)(flat + (size_t)(2 * n)     * DOUT + c);
  bf16_8 y1 = *(const bf16_8*)(flat + (size_t)(2 * n + 1) * DOUT + c);
  const float2 g = *(const float2*)(gates + 2 * n);
  float o[8];
#pragma unroll
  for (int j = 0; j < 8; ++j)
    o[j] = g.x * (float)y0[j] + g.y * (float)y1[j];
  float4* dst = (float4*)(out + (size_t)n * DOUT + c);
  dst[0] = *(float4*)&o[0];
  dst[1] = *(float4*)&o[4];
}

extern "C" void kernel_launch(void* const* d_in, const int* in_sizes, int n_in,
                              void* d_out, int out_size, void* d_ws, size_t ws_size,
                              hipStream_t stream) {
  const float* inputs = (const float*)d_in[0];   // [8192, 2048]
  const float* ew     = (const float*)d_in[1];   // [8, 2048, 2048] (E, out, in)
  const float* gates  = (const float*)d_in[2];   // [8192, 2]
  const int*   ssi    = (const int*)d_in[5];     // sorted_scattered_idxs [16384]
  const int*   offs   = (const int*)d_in[6];     // expert_offsets [8]
  float* out = (float*)d_out;

  // ws layout: bf16 W (64 MB) | bf16 X (32 MB) | bf16 flat out (64 MB)
  __bf16* wsW = (__bf16*)d_ws;
  __bf16* wsX = wsW + (size_t)NEXP * DOUT * DIN;
  __bf16* wsF = wsX + (size_t)NTOK * DIN;

  const int n8w = NEXP * DOUT * DIN / 8;   // 4194304 -> 16384 blocks
  const int n8x = NTOK * DIN / 8;          // 2097152 ->  8192 blocks
  const int nWb = n8w / 256, nXb = n8x / 256;
  cvt_all<<<nWb + nXb, 256, 0, stream>>>((const float4*)ew, (uint4*)wsW,
                                         (const float4*)inputs, (uint4*)wsX, nWb);

  // max M-tiles = 64 + 8 (per-expert ceil padding), 16 N-tiles of 128
  moe_gemm<<<72 * 16, 512, 0, stream>>>(wsX, wsW, ssi, offs, wsF);
  combine<<<NTOK, 256, 0, stream>>>(wsF, gates, out);
}

// Round 8
// 435.083 us; speedup vs baseline: 2.9634x; 1.0218x over previous
//
#include <hip/hip_runtime.h>
#include <hip/hip_bf16.h>
#include <stdint.h>

// Problem constants (fixed by setup_inputs)
#define NTOK   8192
#define TOPK   2
#define NEXP   8
#define DIN    2048
#define DOUT   2048
#define NK     (NTOK*TOPK)

// GEMM tiling: 256(M) x 128(N) tile, BK=32, 8 waves as 4(M) x 2(N),
// wave tile 64x64 = 4x4 MFMA 16x16x32 bf16 frags.
// SHAPE LESSON (R7): the 32x32x16 variant (8 MFMA/K-tile) reads 32 distinct
// rows per half-wave -> ~4-way LDS bank conflict (SQ_LDS_BANK_CONFLICT
// 0 -> 1.78e7, -8% perf). The 16-row frag pattern below measures ZERO.
// REGISTER LESSON (R5): unified VGPR+AGPR pool; 64-reg acc is the max that
// allows 4 waves/SIMD (2 blocks/CU) — 128-reg acc spills (1.9 GB scratch).
// OCCUPANCY LESSON (R1/R2/R4): 1-block/CU lockstep caps at ~33% MfmaUtil;
// the gather's latency stragglers need a co-resident block to hide behind.
#define BM 256
#define BN 128
#define BK 32
#define KTILES  (DIN/BK)           // 64
#define SLOT    24576              // per-K-tile LDS: A 16 KB + B 8 KB
#define NBUF    3                  // 72 KB ring, prefetch depth 2 tiles

typedef __bf16 bf16_8 __attribute__((ext_vector_type(8)));  // 4 VGPRs, MFMA A/B frag
typedef float  f32x4  __attribute__((ext_vector_type(4)));  // MFMA C/D frag

// global->LDS direct load, 16B per lane. LDS dest = wave-uniform base + lane*16.
__device__ __forceinline__ void gl2lds16(const void* g, void* l) {
  auto gp = reinterpret_cast<const __attribute__((address_space(1))) uint32_t*>(
      reinterpret_cast<uintptr_t>(g));
  auto lp = reinterpret_cast<__attribute__((address_space(3))) uint32_t*>(
      reinterpret_cast<uintptr_t>(l));
  __builtin_amdgcn_global_load_lds(gp, lp, 16, 0, 0);
}

// Fused fp32 -> bf16 (RNE) for W then X. 8 elems/thread, 16B stores.
__global__ void cvt_all(const float4* __restrict__ w, uint4* __restrict__ wD,
                        const float4* __restrict__ x, uint4* __restrict__ xD,
                        int nW) {
  int b = blockIdx.x;
  const float4* src;
  uint4* dst;
  int i;
  if (b < nW) { src = w; dst = wD; i = b * 256 + threadIdx.x; }
  else        { src = x; dst = xD; i = (b - nW) * 256 + threadIdx.x; }
  float4 a0 = src[2 * i];
  float4 a1 = src[2 * i + 1];
  union { __bf16 h[8]; uint4 u; } r;
  r.h[0] = (__bf16)a0.x; r.h[1] = (__bf16)a0.y; r.h[2] = (__bf16)a0.z; r.h[3] = (__bf16)a0.w;
  r.h[4] = (__bf16)a1.x; r.h[5] = (__bf16)a1.y; r.h[6] = (__bf16)a1.z; r.h[7] = (__bf16)a1.w;
  dst[i] = r.u;
}

// Grouped GEMM over expert-sorted flat rows — R3 schedule + shape (verbatim,
// 166 us / 39.4% MfmaUtil / 0 LDS conflicts) + XCD-aware bijective block
// swizzle (R6/R7-proven: FETCH 288 -> ~189 MB; same-mtg blocks share an L2).
//
// Per K-tile t (counted-vmcnt NBUF=3 ring, proven in R3):
//   stage(t+2) -> slot (t+2)%3   (3 gload_lds; WAR-safe: slot (t-1)%3's
//                                 reads were consumed before end-of-(t-1)
//                                 barrier, and this issue is after it)
//   ds_read af[0..3], bf[0..3] of tile t; 16 x MFMA 16x16x32
//   s_waitcnt vmcnt(3)           (tile t+1 landed; t+2's 3 stay in flight)
//   s_barrier
// Tail: vmcnt(0) at t=KTILES-2; no sync after last tile.
//
// LDS bank-conflict swizzle (measured 0 conflicts in this exact form):
// row r's 16B chunk q lives at chunk slot q ^ s(r), s(r) = (r>>1)&3.
// Staging lane loads global chunk (tid&3)^((tid>>3)&3); reader xors kq by
// (lr>>1)&3. s(r) invariant under r += multiples of 8.
__global__ __launch_bounds__(512, 4)
void moe_gemm(const __bf16* __restrict__ X,     // [NTOK, DIN] bf16
              const __bf16* __restrict__ W,     // [NEXP, DOUT, DIN] bf16 (B^T form)
              const int* __restrict__ ssi,      // sorted_scattered_idxs [NK]
              const int* __restrict__ offs,     // expert_offsets [NEXP]
              __bf16* __restrict__ flat)        // [NK, DOUT] bf16 out (ungated)
{
  __shared__ char lds[NBUF * SLOT];   // 72 KB ring: per slot A 16 KB | B 8 KB
  __shared__ int  sTok[BM];
  __shared__ int  sF[BM];

  const int tid = threadIdx.x;
  // XCD swizzle: HW assigns XCD = blockIdx % 8; remap so one XCD owns a
  // contiguous chunk of work ids -> same-mtg blocks share an L2. 1152%8==0.
  const int nwg = gridDim.x;
  const int b0  = blockIdx.x;
  const int bid = (b0 & 7) * (nwg >> 3) + (b0 >> 3);
  const int nt  = bid & 15;         // 16 N-tiles of 128
  const int mtg = bid >> 4;         // linear M-tile over all experts

  // Map linear M-tile -> (expert e, tile-in-segment). Uniform scan of 8 offsets.
  int start = 0, end = 0, e, cum = 0, prev = 0, mloc = 0, found = 0;
  for (e = 0; e < NEXP; ++e) {
    int oe  = offs[e];
    int seg = oe - prev;
    int t   = (seg + BM - 1) >> 8;
    if (mtg < cum + t) { start = prev; end = oe; mloc = mtg - cum; found = 1; break; }
    cum += t; prev = oe;
  }
  if (!found) return;  // pad block (uniform exit)

  const int m0 = start + mloc * BM;

  if (tid < BM) {
    int p     = m0 + tid;
    int valid = p < end;
    int f     = ssi[valid ? p : (end - 1)];  // clamp keeps gather in-bounds
    sTok[tid] = f >> 1;                      // token = flat / k (k=2)
    sF[tid]   = valid ? f : -1;
  }
  __syncthreads();   // tables visible; full drain -> clean slate for counted regime

  // Staging: thread tid owns A rows rs = tid>>2 and rs+128, B row rs,
  // swizzled k-chunk kc. LDS dest linear: wave slice base + lane*16.
  const int rs = tid >> 2;                       // 0..127
  const int kc = (tid & 3) ^ ((tid >> 3) & 3);   // swizzled chunk
  const __bf16* pA0 = X + (size_t)sTok[rs]       * DIN + kc * 8;
  const __bf16* pA1 = X + (size_t)sTok[rs + 128] * DIN + kc * 8;
  const __bf16* wBp = W + (size_t)e * DOUT * DIN + (size_t)(nt * BN) * DIN;
  const __bf16* pB0 = wBp + (size_t)rs * DIN + kc * 8;
  char* wsl = (char*)lds + (tid >> 6) * 1024;    // wave-uniform slice base

  // Prologue: stage tiles 0,1 into slots 0,1 (6 loads in flight).
  gl2lds16(pA0, wsl);           gl2lds16(pA1, wsl + 8192);
  gl2lds16(pB0, wsl + 16384);
  pA0 += BK; pA1 += BK; pB0 += BK;
  gl2lds16(pA0, wsl + SLOT);    gl2lds16(pA1, wsl + SLOT + 8192);
  gl2lds16(pB0, wsl + SLOT + 16384);
  pA0 += BK; pA1 += BK; pB0 += BK;   // now at tile-2 source offset

  // Fragment addressing. A frag: lane holds A[m=lr][k=kq*8+j]; LDS row = 64 B.
  const int w   = tid >> 6;
  const int l   = tid & 63;
  const int wm  = w >> 1, wn = w & 1;            // 4 x 2 wave grid
  const int lr  = l & 15;
  const int kq  = l >> 4;
  const int kqs = kq ^ ((lr >> 1) & 3);          // bank-conflict swizzle
  const char* aBase = (const char*)lds + (wm * 64 + lr) * 64 + kqs * 16;
  const char* bBase = (const char*)lds + 16384 + (wn * 64 + lr) * 64 + kqs * 16;

  // Tile 0 arrival: own 3 oldest loads done (tile 1's may stay in flight).
  asm volatile("s_waitcnt vmcnt(3)" ::: "memory");
  __builtin_amdgcn_s_barrier();

  f32x4 acc[4][4] = {};
  int rOff = 0;               // read slot byte offset (t % 3)
  int sOff = 2 * SLOT;        // stage slot byte offset ((t+2) % 3)

  for (int t = 0; t < KTILES; ++t) {
    // Issue next prefetch first (maximizes cover; 3 VMEM issues are cheap).
    if (t < KTILES - 2) {
      char* d = wsl + sOff;
      gl2lds16(pA0, d);  gl2lds16(pA1, d + 8192);  gl2lds16(pB0, d + 16384);
      pA0 += BK; pA1 += BK; pB0 += BK;
      sOff = (sOff == (NBUF - 1) * SLOT) ? 0 : sOff + SLOT;
    }

    const char* aB = aBase + rOff;
    const char* bB = bBase + rOff;
    rOff = (rOff == (NBUF - 1) * SLOT) ? 0 : rOff + SLOT;

    bf16_8 af[4], bf[4];
#pragma unroll
    for (int i = 0; i < 4; ++i) af[i] = *(const bf16_8*)(aB + i * 1024);  // rows i*16
#pragma unroll
    for (int i = 0; i < 4; ++i) bf[i] = *(const bf16_8*)(bB + i * 1024);  // cols i*16

#pragma unroll
    for (int am = 0; am < 4; ++am)
#pragma unroll
      for (int bn = 0; bn < 4; ++bn)
        acc[am][bn] = __builtin_amdgcn_mfma_f32_16x16x32_bf16(
            af[am], bf[bn], acc[am][bn], 0, 0, 0);

    // Arrival of tile t+1 for next iteration; never drain until the tail.
    if (t < KTILES - 2)       { asm volatile("s_waitcnt vmcnt(3)" ::: "memory"); }
    else if (t == KTILES - 2) { asm volatile("s_waitcnt vmcnt(0)" ::: "memory"); }
    if (t < KTILES - 1) __builtin_amdgcn_s_barrier();
  }

  // Epilogue: C/D layout col=lane&15, row=(lane>>4)*4+reg.
  // Plain bf16 stores, ungated; gate applied in combine kernel.
  const int colBase = nt * BN + wn * 64 + lr;
  const int rq = kq * 4;
#pragma unroll
  for (int am = 0; am < 4; ++am) {
#pragma unroll
    for (int v = 0; v < 4; ++v) {
      int rl = wm * 64 + am * 16 + rq + v;
      int f  = sF[rl];
      if (f < 0) continue;
      __bf16* row = flat + (size_t)f * DOUT + colBase;
#pragma unroll
      for (int bn = 0; bn < 4; ++bn)
        row[bn * 16] = (__bf16)acc[am][bn][v];
    }
  }
}

// out[n, :] = g[2n]*flat[2n, :] + g[2n+1]*flat[2n+1, :]
__global__ __launch_bounds__(256)
void combine(const __bf16* __restrict__ flat, const float* __restrict__ gates,
             float* __restrict__ out) {
  const int n = blockIdx.x;
  const int c = threadIdx.x * 8;
  bf16_8 y0 = *(const bf16_8*)(flat + (size_t)(2 * n)     * DOUT + c);
  bf16_8 y1 = *(const bf16_8*)(flat + (size_t)(2 * n + 1) * DOUT + c);
  const float2 g = *(const float2*)(gates + 2 * n);
  float o[8];
#pragma unroll
  for (int j = 0; j < 8; ++j)
    o[j] = g.x * (float)y0[j] + g.y * (float)y1[j];
  float4* dst = (float4*)(out + (size_t)n * DOUT + c);
  dst[0] = *(float4*)&o[0];
  dst[1] = *(float4*)&o[4];
}

extern "C" void kernel_launch(void* const* d_in, const int* in_sizes, int n_in,
                              void* d_out, int out_size, void* d_ws, size_t ws_size,
                              hipStream_t stream) {
  const float* inputs = (const float*)d_in[0];   // [8192, 2048]
  const float* ew     = (const float*)d_in[1];   // [8, 2048, 2048] (E, out, in)
  const float* gates  = (const float*)d_in[2];   // [8192, 2]
  const int*   ssi    = (const int*)d_in[5];     // sorted_scattered_idxs [16384]
  const int*   offs   = (const int*)d_in[6];     // expert_offsets [8]
  float* out = (float*)d_out;

  // ws layout: bf16 W (64 MB) | bf16 X (32 MB) | bf16 flat out (64 MB)
  __bf16* wsW = (__bf16*)d_ws;
  __bf16* wsX = wsW + (size_t)NEXP * DOUT * DIN;
  __bf16* wsF = wsX + (size_t)NTOK * DIN;

  const int n8w = NEXP * DOUT * DIN / 8;   // 4194304 -> 16384 blocks
  const int n8x = NTOK * DIN / 8;          // 2097152 ->  8192 blocks
  const int nWb = n8w / 256, nXb = n8x / 256;
  cvt_all<<<nWb + nXb, 256, 0, stream>>>((const float4*)ew, (uint4*)wsW,
                                         (const float4*)inputs, (uint4*)wsX, nWb);

  // max M-tiles = 64 + 8 (per-expert ceil padding), 16 N-tiles of 128
  moe_gemm<<<72 * 16, 512, 0, stream>>>(wsX, wsW, ssi, offs, wsF);
  combine<<<NTOK, 256, 0, stream>>>(wsF, gates, out);
}